// Round 1
// baseline (101.356 us; speedup 1.0000x reference)
//
#include <hip/hip_runtime.h>

#define HCH 32
#define NDIM 1024
#define SEG 512                  // pixels per wave (half row)
#define PAIRS (SEG / 64)         // 8 iterations of 64 px (2 MFMA tiles)

using half2v   = __attribute__((ext_vector_type(2))) _Float16;
using half8    = __attribute__((ext_vector_type(8))) _Float16;
using floatx16 = __attribute__((ext_vector_type(16))) float;

// One wave per half-row (b,i,seg).
// Stage the wave's whole d/wj stream (512 px each) into private LDS with
// 4x global_load_dwordx4 up front (4 KB in flight/wave -> HBM latency-BW
// covered), then run 8x 64-px pairs entirely from LDS:
//   layer1 packed f16 -> 2x v_mfma_f32_32x32x16_f16 per tile (D[ch][px]),
//   f32 relu+fma dot with W3 per tile, ONE shfl_xor(32) resolves both tiles,
//   softplus f32, one coalesced 256B store (all 64 lanes).
//
// R1 change: __launch_bounds__(256, 2) instead of (256, 4).
// Peak live set is ~129 VGPRs (invariants 71 + frags 16 + accA/accB 32 +
// temps ~10); the old 128-VGPR cap forced by min-4-waves/EU sat exactly on
// that boundary -> spills / pressure-serialized schedule. Cap 256 makes the
// kernel spill-free at ~3 waves/SIMD.
__global__ __launch_bounds__(256, 2)
void lf_kernel(const float* __restrict__ weights,
               const float* __restrict__ distances,
               const float* __restrict__ W1,
               const float* __restrict__ b1,
               const float* __restrict__ W2,
               const float* __restrict__ b2,
               const float* __restrict__ W3,
               const float* __restrict__ b3,
               float* __restrict__ out)
{
    __shared__ float sd[4][SEG];   // per-wave private d chunk (2 KB/wave)
    __shared__ float sw[4][SEG];   // per-wave private wj chunk

    const int lane = threadIdx.x & 63;
    const int wv = threadIdx.x >> 6;
    const int wave_gid = __builtin_amdgcn_readfirstlane(blockIdx.x * 4 + wv);
    const int row_id = wave_gid >> 1;          // (b,i) row
    const int j_begin = (wave_gid & 1) * SEG;  // half within the row
    const int b = row_id >> 10;                // N = 1024

    const int col = lane & 31;                 // pixel-in-tile (B n-index, D col)
    const int half_id = lane >> 5;
    const bool hi = (half_id != 0);
    const int kb = half_id * 8;                // k-block base for A/B frags

    const float* __restrict__ drow = distances + (size_t)row_id * NDIM + j_begin;
    const float* __restrict__ wrow = weights + b * NDIM + j_begin;
    float* __restrict__ orow = out + (size_t)row_id * NDIM + j_begin;

    // ---- Issue the bulk stream loads FIRST (16 B/lane x4 = 4 KB in flight) ----
    const float4 dv0 = *(const float4*)(drow + 4 * lane);
    const float4 dv1 = *(const float4*)(drow + 256 + 4 * lane);
    const float4 wv0 = *(const float4*)(wrow + 4 * lane);
    const float4 wv1 = *(const float4*)(wrow + 256 + 4 * lane);

    // ---- Weight prologue (overlaps the stream loads) ----
    const float wi = weights[row_id];

    // Layer-1 constants as f16 pairs. Pair p<4 -> channels kb+2p,+1 (frag0);
    // p>=4 -> 16+kb+2(p-4)+{0,1} (frag1). base = W1[0,ch]*wi + b1[ch] (f32 fold).
    half2v base2[8], cc2[8], ee2[8];
#pragma unroll
    for (int p = 0; p < 8; ++p) {
        const int chA = (p < 4) ? (kb + 2 * p) : (16 + kb + 2 * (p - 4));
        const int chB = chA + 1;
        base2[p] = half2v{(_Float16)fmaf(W1[chA], wi, b1[chA]),
                          (_Float16)fmaf(W1[chB], wi, b1[chB])};
        cc2[p] = half2v{(_Float16)W1[HCH + chA], (_Float16)W1[HCH + chB]};
        ee2[p] = half2v{(_Float16)W1[2 * HCH + chA], (_Float16)W1[2 * HCH + chB]};
    }

    // A fragments: A[m=c][k=h] = W2[h][c]; c = col, h = kb+j / 16+kb+j.
    half8 a0, a1;
#pragma unroll
    for (int j = 0; j < 8; ++j) {
        a0[j] = (_Float16)W2[(kb + j) * HCH + col];
        a1[j] = (_Float16)W2[(16 + kb + j) * HCH + col];
    }

    // C-init = b2 broadcast along cols; W3 gathered per accumulator register.
    // D row for reg r: (r&3) + 8*(r>>2) + 4*half_id  [measured C/D layout, 32x32]
    floatx16 cinit;
    float w3r[16];
#pragma unroll
    for (int r = 0; r < 16; ++r) {
        const int rc = (r & 3) + 8 * (r >> 2) + 4 * half_id;
        cinit[r] = b2[rc];
        w3r[r]   = W3[rc];
    }
    const float b3v = b3[0];

    // ---- Park the streams in LDS (vmcnt waits happen here) ----
    *(float4*)&sd[wv][4 * lane]       = dv0;
    *(float4*)&sd[wv][256 + 4 * lane] = dv1;
    *(float4*)&sw[wv][4 * lane]       = wv0;
    *(float4*)&sw[wv][256 + 4 * lane] = wv1;
    __syncthreads();

    const half2v zero2 = half2v{(_Float16)0.0f, (_Float16)0.0f};

#pragma unroll
    for (int p = 0; p < PAIRS; ++p) {
        // Stream values from LDS: lanes 0..31 / 32..63 read identical
        // addresses (broadcast, conflict-free).
        const float dA = sd[wv][p * 64 + col];
        const float dB = sd[wv][p * 64 + 32 + col];
        const float wA = sw[wv][p * 64 + col];
        const float wB = sw[wv][p * 64 + 32 + col];

        // ---- Layer 1 (packed f16), two independent tiles ----
        const _Float16 dhA = (_Float16)dA, wjhA = (_Float16)wA;
        const _Float16 dhB = (_Float16)dB, wjhB = (_Float16)wB;
        const half2v d2A = half2v{dhA, dhA}, wj2A = half2v{wjhA, wjhA};
        const half2v d2B = half2v{dhB, dhB}, wj2B = half2v{wjhB, wjhB};

        union Frag { half8 v; half2v h[4]; } f0A, f1A, f0B, f1B;
#pragma unroll
        for (int q = 0; q < 4; ++q) {
            half2v tA0 = __builtin_elementwise_fma(cc2[q], wj2A, base2[q]);
            tA0 = __builtin_elementwise_fma(ee2[q], d2A, tA0);
            f0A.h[q] = __builtin_elementwise_max(tA0, zero2);
            half2v tA1 = __builtin_elementwise_fma(cc2[q + 4], wj2A, base2[q + 4]);
            tA1 = __builtin_elementwise_fma(ee2[q + 4], d2A, tA1);
            f1A.h[q] = __builtin_elementwise_max(tA1, zero2);
            half2v tB0 = __builtin_elementwise_fma(cc2[q], wj2B, base2[q]);
            tB0 = __builtin_elementwise_fma(ee2[q], d2B, tB0);
            f0B.h[q] = __builtin_elementwise_max(tB0, zero2);
            half2v tB1 = __builtin_elementwise_fma(cc2[q + 4], wj2B, base2[q + 4]);
            tB1 = __builtin_elementwise_fma(ee2[q + 4], d2B, tB1);
            f1B.h[q] = __builtin_elementwise_max(tB1, zero2);
        }

        // ---- Layer 2: two independent MFMA chains ----
        floatx16 accA = __builtin_amdgcn_mfma_f32_32x32x16_f16(a0, f0A.v, cinit, 0, 0, 0);
        floatx16 accB = __builtin_amdgcn_mfma_f32_32x32x16_f16(a0, f0B.v, cinit, 0, 0, 0);
        accA = __builtin_amdgcn_mfma_f32_32x32x16_f16(a1, f1A.v, accA, 0, 0, 0);
        accB = __builtin_amdgcn_mfma_f32_32x32x16_f16(a1, f1B.v, accB, 0, 0, 0);

        // ---- Layer 3: relu + W3 dot, two tiles interleaved ----
        float sA0 = 0.0f, sA1 = 0.0f, sB0 = 0.0f, sB1 = 0.0f;
#pragma unroll
        for (int r = 0; r < 16; r += 2) {
            sA0 = fmaf(fmaxf(accA[r + 0], 0.0f), w3r[r + 0], sA0);
            sA1 = fmaf(fmaxf(accA[r + 1], 0.0f), w3r[r + 1], sA1);
            sB0 = fmaf(fmaxf(accB[r + 0], 0.0f), w3r[r + 0], sB0);
            sB1 = fmaf(fmaxf(accB[r + 1], 0.0f), w3r[r + 1], sB1);
        }
        const float sA = sA0 + sA1;
        const float sB = sB0 + sB1;

        // One shuffle resolves both tiles: send the tile the other half needs.
        const float u = hi ? sA : sB;
        const float other = __shfl_xor(u, 32, 64);
        const float loc = hi ? sB : sA;
        const float full = loc + other;  // lane<32: tileA col; lane>=32: tileB col

        // softplus(x) = max(x,0) + log(1 + exp(-|x|)), 64 distinct pixels
        const float x = full + b3v;
        const float sp = fmaxf(x, 0.0f) + __logf(1.0f + __expf(-fabsf(x)));

        orow[p * 64 + lane] = sp;  // coalesced 256B, all 64 lanes

    }
}

extern "C" void kernel_launch(void* const* d_in, const int* in_sizes, int n_in,
                              void* d_out, int out_size, void* d_ws, size_t ws_size,
                              hipStream_t stream) {
    const float* weights   = (const float*)d_in[0];
    const float* distances = (const float*)d_in[1];
    const float* W1 = (const float*)d_in[2];
    const float* b1 = (const float*)d_in[3];
    const float* W2 = (const float*)d_in[4];
    const float* b2 = (const float*)d_in[5];
    const float* W3 = (const float*)d_in[6];
    const float* b3 = (const float*)d_in[7];
    float* out = (float*)d_out;

    const int rows_total = 4 * 1024;            // B * N
    dim3 grid(rows_total * (NDIM / SEG) / 4);   // 2048 blocks, 4 waves each
    lf_kernel<<<grid, 256, 0, stream>>>(weights, distances, W1, b1, W2, b2, W3, b3, out);
}

// Round 2
// 101.243 us; speedup vs baseline: 1.0011x; 1.0011x over previous
//
#include <hip/hip_runtime.h>

#define HCH 32
#define NDIM 1024
#define SEG 512                  // pixels per wave (half row)
#define PAIRS (SEG / 64)         // 8 iterations of 64 px (2 MFMA tiles)

using half2v   = __attribute__((ext_vector_type(2))) _Float16;
using half8    = __attribute__((ext_vector_type(8))) _Float16;
using floatx16 = __attribute__((ext_vector_type(16))) float;
using float2v  = __attribute__((ext_vector_type(2))) float;

// One wave per half-row (b,i,seg).
// Stage the wave's whole d/wj stream (512 px each) into private LDS with
// 4x global_load_dwordx4 up front, then run 8x 64-px pairs entirely from LDS:
//   layer1 packed f16 -> 2x v_mfma_f32_32x32x16_f16 per tile (D[ch][px]),
//   layer3 relu+dot in PACKED f32 (v_pk_max_f32 / v_pk_fma_f32),
//   ONE shfl_xor(32) resolves both tiles, softplus f32, coalesced 256B store.
//
// R2 change: layer-3 relu+W3-dot moved from 64 scalar f32 ops/iter to 32
// VOP3P packed ops (float2v elementwise max/fma over the MFMA acc register
// pairs, which are naturally even-aligned). Pair-sums folded into the packed
// accumulators. ~12% VALU cut, numerics identical.
// (Profile evidence: lf_kernel absent from top-5 => < 44 us/dispatch; timed
// 101.4 us is dominated by harness 256 MiB poison fills at ~6 TB/s. This
// change discriminates the kernel's true share of dur_us.)
__global__ __launch_bounds__(256, 2)
void lf_kernel(const float* __restrict__ weights,
               const float* __restrict__ distances,
               const float* __restrict__ W1,
               const float* __restrict__ b1,
               const float* __restrict__ W2,
               const float* __restrict__ b2,
               const float* __restrict__ W3,
               const float* __restrict__ b3,
               float* __restrict__ out)
{
    __shared__ float sd[4][SEG];   // per-wave private d chunk (2 KB/wave)
    __shared__ float sw[4][SEG];   // per-wave private wj chunk

    const int lane = threadIdx.x & 63;
    const int wv = threadIdx.x >> 6;
    const int wave_gid = __builtin_amdgcn_readfirstlane(blockIdx.x * 4 + wv);
    const int row_id = wave_gid >> 1;          // (b,i) row
    const int j_begin = (wave_gid & 1) * SEG;  // half within the row
    const int b = row_id >> 10;                // N = 1024

    const int col = lane & 31;                 // pixel-in-tile (B n-index, D col)
    const int half_id = lane >> 5;
    const bool hi = (half_id != 0);
    const int kb = half_id * 8;                // k-block base for A/B frags

    const float* __restrict__ drow = distances + (size_t)row_id * NDIM + j_begin;
    const float* __restrict__ wrow = weights + b * NDIM + j_begin;
    float* __restrict__ orow = out + (size_t)row_id * NDIM + j_begin;

    // ---- Issue the bulk stream loads FIRST (16 B/lane x4 = 4 KB in flight) ----
    const float4 dv0 = *(const float4*)(drow + 4 * lane);
    const float4 dv1 = *(const float4*)(drow + 256 + 4 * lane);
    const float4 wv0 = *(const float4*)(wrow + 4 * lane);
    const float4 wv1 = *(const float4*)(wrow + 256 + 4 * lane);

    // ---- Weight prologue (overlaps the stream loads) ----
    const float wi = weights[row_id];

    // Layer-1 constants as f16 pairs. Pair p<4 -> channels kb+2p,+1 (frag0);
    // p>=4 -> 16+kb+2(p-4)+{0,1} (frag1). base = W1[0,ch]*wi + b1[ch] (f32 fold).
    half2v base2[8], cc2[8], ee2[8];
#pragma unroll
    for (int p = 0; p < 8; ++p) {
        const int chA = (p < 4) ? (kb + 2 * p) : (16 + kb + 2 * (p - 4));
        const int chB = chA + 1;
        base2[p] = half2v{(_Float16)fmaf(W1[chA], wi, b1[chA]),
                          (_Float16)fmaf(W1[chB], wi, b1[chB])};
        cc2[p] = half2v{(_Float16)W1[HCH + chA], (_Float16)W1[HCH + chB]};
        ee2[p] = half2v{(_Float16)W1[2 * HCH + chA], (_Float16)W1[2 * HCH + chB]};
    }

    // A fragments: A[m=c][k=h] = W2[h][c]; c = col, h = kb+j / 16+kb+j.
    half8 a0, a1;
#pragma unroll
    for (int j = 0; j < 8; ++j) {
        a0[j] = (_Float16)W2[(kb + j) * HCH + col];
        a1[j] = (_Float16)W2[(16 + kb + j) * HCH + col];
    }

    // C-init = b2 broadcast along cols; W3 gathered per accumulator register,
    // stored as float2 pairs matching acc register pairs (even-aligned for
    // VOP3P pk ops).
    // D row for reg r: (r&3) + 8*(r>>2) + 4*half_id  [measured C/D layout, 32x32]
    floatx16 cinit;
    float2v w32[8];
#pragma unroll
    for (int r = 0; r < 16; r += 2) {
        const int rc0 = ((r + 0) & 3) + 8 * ((r + 0) >> 2) + 4 * half_id;
        const int rc1 = ((r + 1) & 3) + 8 * ((r + 1) >> 2) + 4 * half_id;
        cinit[r + 0] = b2[rc0];
        cinit[r + 1] = b2[rc1];
        w32[r >> 1] = float2v{W3[rc0], W3[rc1]};
    }
    const float b3v = b3[0];

    // ---- Park the streams in LDS (vmcnt waits happen here) ----
    *(float4*)&sd[wv][4 * lane]       = dv0;
    *(float4*)&sd[wv][256 + 4 * lane] = dv1;
    *(float4*)&sw[wv][4 * lane]       = wv0;
    *(float4*)&sw[wv][256 + 4 * lane] = wv1;
    __syncthreads();

    const half2v zero2 = half2v{(_Float16)0.0f, (_Float16)0.0f};
    const float2v zf2 = float2v{0.0f, 0.0f};

#pragma unroll
    for (int p = 0; p < PAIRS; ++p) {
        // Stream values from LDS: lanes 0..31 / 32..63 read identical
        // addresses (broadcast, conflict-free).
        const float dA = sd[wv][p * 64 + col];
        const float dB = sd[wv][p * 64 + 32 + col];
        const float wA = sw[wv][p * 64 + col];
        const float wB = sw[wv][p * 64 + 32 + col];

        // ---- Layer 1 (packed f16), two independent tiles ----
        const _Float16 dhA = (_Float16)dA, wjhA = (_Float16)wA;
        const _Float16 dhB = (_Float16)dB, wjhB = (_Float16)wB;
        const half2v d2A = half2v{dhA, dhA}, wj2A = half2v{wjhA, wjhA};
        const half2v d2B = half2v{dhB, dhB}, wj2B = half2v{wjhB, wjhB};

        union Frag { half8 v; half2v h[4]; } f0A, f1A, f0B, f1B;
#pragma unroll
        for (int q = 0; q < 4; ++q) {
            half2v tA0 = __builtin_elementwise_fma(cc2[q], wj2A, base2[q]);
            tA0 = __builtin_elementwise_fma(ee2[q], d2A, tA0);
            f0A.h[q] = __builtin_elementwise_max(tA0, zero2);
            half2v tA1 = __builtin_elementwise_fma(cc2[q + 4], wj2A, base2[q + 4]);
            tA1 = __builtin_elementwise_fma(ee2[q + 4], d2A, tA1);
            f1A.h[q] = __builtin_elementwise_max(tA1, zero2);
            half2v tB0 = __builtin_elementwise_fma(cc2[q], wj2B, base2[q]);
            tB0 = __builtin_elementwise_fma(ee2[q], d2B, tB0);
            f0B.h[q] = __builtin_elementwise_max(tB0, zero2);
            half2v tB1 = __builtin_elementwise_fma(cc2[q + 4], wj2B, base2[q + 4]);
            tB1 = __builtin_elementwise_fma(ee2[q + 4], d2B, tB1);
            f1B.h[q] = __builtin_elementwise_max(tB1, zero2);
        }

        // ---- Layer 2: two independent MFMA chains ----
        floatx16 accA = __builtin_amdgcn_mfma_f32_32x32x16_f16(a0, f0A.v, cinit, 0, 0, 0);
        floatx16 accB = __builtin_amdgcn_mfma_f32_32x32x16_f16(a0, f0B.v, cinit, 0, 0, 0);
        accA = __builtin_amdgcn_mfma_f32_32x32x16_f16(a1, f1A.v, accA, 0, 0, 0);
        accB = __builtin_amdgcn_mfma_f32_32x32x16_f16(a1, f1B.v, accB, 0, 0, 0);

        // ---- Layer 3: relu + W3 dot in packed f32 (VOP3P) ----
        // Two independent packed accumulators per tile for ILP; acc register
        // pairs (r, r+1) are even-aligned (MFMA acc is 16-aligned).
        float2v sA2a = zf2, sA2b = zf2, sB2a = zf2, sB2b = zf2;
#pragma unroll
        for (int r = 0; r < 16; r += 4) {
            const float2v aA0 = float2v{accA[r + 0], accA[r + 1]};
            const float2v aA1 = float2v{accA[r + 2], accA[r + 3]};
            const float2v aB0 = float2v{accB[r + 0], accB[r + 1]};
            const float2v aB1 = float2v{accB[r + 2], accB[r + 3]};
            sA2a = __builtin_elementwise_fma(__builtin_elementwise_max(aA0, zf2), w32[(r >> 1) + 0], sA2a);
            sA2b = __builtin_elementwise_fma(__builtin_elementwise_max(aA1, zf2), w32[(r >> 1) + 1], sA2b);
            sB2a = __builtin_elementwise_fma(__builtin_elementwise_max(aB0, zf2), w32[(r >> 1) + 0], sB2a);
            sB2b = __builtin_elementwise_fma(__builtin_elementwise_max(aB1, zf2), w32[(r >> 1) + 1], sB2b);
        }
        const float2v sA2 = sA2a + sA2b;
        const float2v sB2 = sB2a + sB2b;
        const float sA = sA2[0] + sA2[1];
        const float sB = sB2[0] + sB2[1];

        // One shuffle resolves both tiles: send the tile the other half needs.
        const float u = hi ? sA : sB;
        const float other = __shfl_xor(u, 32, 64);
        const float loc = hi ? sB : sA;
        const float full = loc + other;  // lane<32: tileA col; lane>=32: tileB col

        // softplus(x) = max(x,0) + log(1 + exp(-|x|)), 64 distinct pixels
        const float x = full + b3v;
        const float sp = fmaxf(x, 0.0f) + __logf(1.0f + __expf(-fabsf(x)));

        orow[p * 64 + lane] = sp;  // coalesced 256B, all 64 lanes

    }
}

extern "C" void kernel_launch(void* const* d_in, const int* in_sizes, int n_in,
                              void* d_out, int out_size, void* d_ws, size_t ws_size,
                              hipStream_t stream) {
    const float* weights   = (const float*)d_in[0];
    const float* distances = (const float*)d_in[1];
    const float* W1 = (const float*)d_in[2];
    const float* b1 = (const float*)d_in[3];
    const float* W2 = (const float*)d_in[4];
    const float* b2 = (const float*)d_in[5];
    const float* W3 = (const float*)d_in[6];
    const float* b3 = (const float*)d_in[7];
    float* out = (float*)d_out;

    const int rows_total = 4 * 1024;            // B * N
    dim3 grid(rows_total * (NDIM / SEG) / 4);   // 2048 blocks, 4 waves each
    lf_kernel<<<grid, 256, 0, stream>>>(weights, distances, W1, b1, W2, b2, W3, b3, out);
}